// Round 2
// baseline (1330.149 us; speedup 1.0000x reference)
//
#include <hip/hip_runtime.h>

#define TT 2048
#define BB 64
#define HH 256   // EMB == HID == 256

typedef _Float16 half2_t __attribute__((ext_vector_type(2)));
typedef _Float16 half8_t __attribute__((ext_vector_type(8)));
typedef float f32x4 __attribute__((ext_vector_type(4)));

// ---------------------------------------------------------------------------
// prep: transpose + fp16-convert W_ih and W_hh into [N][K] row-major.
// ---------------------------------------------------------------------------
__global__ void prep_kernel(const float* __restrict__ Wih, const float* __restrict__ Whh,
                            _Float16* __restrict__ WihT, _Float16* __restrict__ WhhT) {
  const int n = blockIdx.x;   // output column
  const int k = threadIdx.x;  // input row
  WihT[n * HH + k] = (_Float16)Wih[k * HH + n];
  WhhT[n * HH + k] = (_Float16)Whh[k * HH + n];
}

// ---------------------------------------------------------------------------
// Part A: U[t][b][n] = (emb[source[b][t]] @ W_ih)[n] + b_ih[n] + b_hh[n], fp16.
// (unchanged from R1 — verified correct; scan dominates runtime)
// ---------------------------------------------------------------------------
__global__ __launch_bounds__(256, 2) void embed_gemm_kernel(
    const int* __restrict__ source, const float* __restrict__ emb,
    const _Float16* __restrict__ WihT, const float* __restrict__ b_ih,
    const float* __restrict__ b_hh, _Float16* __restrict__ U) {
  const int t = blockIdx.x;
  const int nbase = blockIdx.y * 64;
  __shared__ __align__(16) _Float16 Bs[64][280];

  const int tid = threadIdx.x;
  for (int c = tid; c < 64 * 32; c += 256) {
    const int n = c >> 5;
    const int ko = (c & 31) * 8;
    *(half8_t*)&Bs[n][ko] = *(const half8_t*)(WihT + (size_t)(nbase + n) * HH + ko);
  }
  __syncthreads();

  const int lane = tid & 63;
  const int wave = tid >> 6;
  const int row16 = lane & 15;
  const int quad = lane >> 4;
  const int b = wave * 16 + row16;              // A-fragment row = batch
  const int src = source[b * TT + t];           // source is [B][T]
  const float* arow = emb + (size_t)src * HH + quad * 8;

  f32x4 acc[4];
#pragma unroll
  for (int ct = 0; ct < 4; ++ct) acc[ct] = (f32x4){0.f, 0.f, 0.f, 0.f};

#pragma unroll
  for (int kt = 0; kt < 8; ++kt) {
    const float4 x0 = *(const float4*)(arow + kt * 32);
    const float4 x1 = *(const float4*)(arow + kt * 32 + 4);
    half8_t af;
    af[0] = (_Float16)x0.x; af[1] = (_Float16)x0.y;
    af[2] = (_Float16)x0.z; af[3] = (_Float16)x0.w;
    af[4] = (_Float16)x1.x; af[5] = (_Float16)x1.y;
    af[6] = (_Float16)x1.z; af[7] = (_Float16)x1.w;
#pragma unroll
    for (int ct = 0; ct < 4; ++ct) {
      const half8_t bf = *(const half8_t*)&Bs[ct * 16 + row16][quad * 8 + kt * 32];
      acc[ct] = __builtin_amdgcn_mfma_f32_16x16x32_f16(af, bf, acc[ct], 0, 0, 0);
    }
  }

#pragma unroll
  for (int ct = 0; ct < 4; ++ct) {
    const int nn = nbase + ct * 16 + row16;     // C col = lane&15
    const float bias = b_ih[nn] + b_hh[nn];
#pragma unroll
    for (int r = 0; r < 4; ++r) {
      const int bb = wave * 16 + quad * 4 + r;  // C row = quad*4 + reg
      U[((size_t)t * BB + bb) * HH + nn] = (_Float16)(acc[ct][r] + bias);
    }
  }
}

// ---------------------------------------------------------------------------
// Part B: recurrence, k-split across waves.
//   Wave w owns k in [64w, 64w+64). Lane l owns outputs {l, l+64, l+128, l+192}.
//   Phase 1: 8 broadcast ds_read_b128 of my h-quarter (vs 32 full-h before),
//            128 fdot2 in 8 independent chains, 4 partial writes
//            (consecutive dwords -> 2-way bank aliasing = free).
//   Phase 2 (after barrier): thread j sums 4 partials + u_j, tanh, writes h_j.
//   Single h buffer: barrier 1 separates all phase-1 h-reads from the write.
//   LDS wave-insts/step: ~60 vs 132 before — the pipe was the bottleneck.
// ---------------------------------------------------------------------------
__global__ __launch_bounds__(256, 1) void rnn_scan_kernel(
    const _Float16* __restrict__ U, const _Float16* __restrict__ WhhT,
    float* __restrict__ out) {
  const int b = blockIdx.x;
  const int tid = threadIdx.x;
  const int w = tid >> 6;   // wave index = k-quarter
  const int l = tid & 63;   // lane

  __shared__ __align__(16) _Float16 hbuf[HH];   // 512 B
  __shared__ __align__(16) float pbuf[4 * HH];  // 4 KB partials p[w][j]

  // Weights: wreg[q][i] = W^T[l+64q][64w+8i .. +8)  (128 VGPRs)
  half8_t wreg[4][8];
#pragma unroll
  for (int q = 0; q < 4; ++q) {
    const _Float16* base = WhhT + (size_t)(l + 64 * q) * HH + 64 * w;
#pragma unroll
    for (int i = 0; i < 8; ++i) wreg[q][i] = *(const half8_t*)(base + 8 * i);
  }

  hbuf[tid] = (_Float16)0.f;  // h0 = 0
  const _Float16* Up = U + b * HH + tid;
  _Float16 u_next = Up[0];
  float hn = 0.f;
  __syncthreads();

  for (int t = 0; t < TT; ++t) {
    const float u_cur = (float)u_next;
    // prefetch next step's u (2 barriers between issue and use -> fully hidden)
    u_next = Up[(size_t)((t + 1) & (TT - 1)) * (BB * HH)];

    // ---- phase 1: partial dots over my k-quarter ----
    const half8_t* hq = (const half8_t*)(hbuf + 64 * w);
    half8_t hv[8];
#pragma unroll
    for (int i = 0; i < 8; ++i) hv[i] = hq[i];  // 8 broadcast b128 reads

    float pa[4];
#pragma unroll
    for (int q = 0; q < 4; ++q) {
      float a0 = 0.f, a1 = 0.f;
#pragma unroll
      for (int i = 0; i < 8; ++i) {
        const half8_t h8 = hv[i];
        const half8_t w8 = wreg[q][i];
        a0 = __builtin_amdgcn_fdot2((half2_t){h8[0], h8[1]}, (half2_t){w8[0], w8[1]}, a0, false);
        a1 = __builtin_amdgcn_fdot2((half2_t){h8[2], h8[3]}, (half2_t){w8[2], w8[3]}, a1, false);
        a0 = __builtin_amdgcn_fdot2((half2_t){h8[4], h8[5]}, (half2_t){w8[4], w8[5]}, a0, false);
        a1 = __builtin_amdgcn_fdot2((half2_t){h8[6], h8[7]}, (half2_t){w8[6], w8[7]}, a1, false);
      }
      pa[q] = a0 + a1;
    }
#pragma unroll
    for (int q = 0; q < 4; ++q) pbuf[w * HH + 64 * q + l] = pa[q];

    __syncthreads();  // barrier 1: partials visible; all h-reads done

    // ---- phase 2: thread j = tid reduces output j ----
    const float a = u_cur + ((pbuf[tid] + pbuf[HH + tid]) +
                             (pbuf[2 * HH + tid] + pbuf[3 * HH + tid]));
    // tanh(a) = 1 - 2/(exp(2a)+1)
    const float e = __builtin_amdgcn_exp2f(a * 2.885390081777927f);  // 2*log2(e)
    hn = 1.f - 2.f * __builtin_amdgcn_rcpf(e + 1.f);
    hbuf[tid] = (_Float16)hn;

    __syncthreads();  // barrier 2: h + pbuf safe to touch next step
  }
  out[(size_t)b * HH + tid] = hn;
}

// ---------------------------------------------------------------------------
extern "C" void kernel_launch(void* const* d_in, const int* in_sizes, int n_in,
                              void* d_out, int out_size, void* d_ws, size_t ws_size,
                              hipStream_t stream) {
  const int*   source = (const int*)d_in[0];
  const float* emb    = (const float*)d_in[1];
  const float* Wih    = (const float*)d_in[2];
  const float* Whh    = (const float*)d_in[3];
  const float* bih    = (const float*)d_in[4];
  const float* bhh    = (const float*)d_in[5];
  float* out = (float*)d_out;

  char* ws = (char*)d_ws;
  _Float16* U    = (_Float16*)ws;                    // 2048*64*256*2 = 67,108,864 B
  _Float16* WihT = (_Float16*)(ws + 67108864);       // 131,072 B
  _Float16* WhhT = (_Float16*)(ws + 67239936);       // 131,072 B (total ~67.4 MB)

  prep_kernel<<<dim3(256), dim3(256), 0, stream>>>(Wih, Whh, WihT, WhhT);
  embed_gemm_kernel<<<dim3(TT, 4), dim3(256), 0, stream>>>(source, emb, WihT, bih, bhh, U);
  rnn_scan_kernel<<<dim3(BB), dim3(256), 0, stream>>>(U, WhhT, out);
}

// Round 3
// 1229.533 us; speedup vs baseline: 1.0818x; 1.0818x over previous
//
#include <hip/hip_runtime.h>

#define TT 2048
#define BB 64
#define HH 256   // EMB == HID == 256

typedef _Float16 half2_t __attribute__((ext_vector_type(2)));
typedef _Float16 half8_t __attribute__((ext_vector_type(8)));
typedef float f32x4 __attribute__((ext_vector_type(4)));

// ---------------------------------------------------------------------------
// prep: transpose + fp16-convert W_ih and W_hh into [N][K] row-major.
// ---------------------------------------------------------------------------
__global__ void prep_kernel(const float* __restrict__ Wih, const float* __restrict__ Whh,
                            _Float16* __restrict__ WihT, _Float16* __restrict__ WhhT) {
  const int n = blockIdx.x;   // output column
  const int k = threadIdx.x;  // input row
  WihT[n * HH + k] = (_Float16)Wih[k * HH + n];
  WhhT[n * HH + k] = (_Float16)Whh[k * HH + n];
}

// ---------------------------------------------------------------------------
// Part A: U[t][b][n] = (emb[source[b][t]] @ W_ih)[n] + b_ih[n] + b_hh[n], fp16.
// (unchanged — verified correct; scan dominates runtime)
// ---------------------------------------------------------------------------
__global__ __launch_bounds__(256, 2) void embed_gemm_kernel(
    const int* __restrict__ source, const float* __restrict__ emb,
    const _Float16* __restrict__ WihT, const float* __restrict__ b_ih,
    const float* __restrict__ b_hh, _Float16* __restrict__ U) {
  const int t = blockIdx.x;
  const int nbase = blockIdx.y * 64;
  __shared__ __align__(16) _Float16 Bs[64][280];

  const int tid = threadIdx.x;
  for (int c = tid; c < 64 * 32; c += 256) {
    const int n = c >> 5;
    const int ko = (c & 31) * 8;
    *(half8_t*)&Bs[n][ko] = *(const half8_t*)(WihT + (size_t)(nbase + n) * HH + ko);
  }
  __syncthreads();

  const int lane = tid & 63;
  const int wave = tid >> 6;
  const int row16 = lane & 15;
  const int quad = lane >> 4;
  const int b = wave * 16 + row16;              // A-fragment row = batch
  const int src = source[b * TT + t];           // source is [B][T]
  const float* arow = emb + (size_t)src * HH + quad * 8;

  f32x4 acc[4];
#pragma unroll
  for (int ct = 0; ct < 4; ++ct) acc[ct] = (f32x4){0.f, 0.f, 0.f, 0.f};

#pragma unroll
  for (int kt = 0; kt < 8; ++kt) {
    const float4 x0 = *(const float4*)(arow + kt * 32);
    const float4 x1 = *(const float4*)(arow + kt * 32 + 4);
    half8_t af;
    af[0] = (_Float16)x0.x; af[1] = (_Float16)x0.y;
    af[2] = (_Float16)x0.z; af[3] = (_Float16)x0.w;
    af[4] = (_Float16)x1.x; af[5] = (_Float16)x1.y;
    af[6] = (_Float16)x1.z; af[7] = (_Float16)x1.w;
#pragma unroll
    for (int ct = 0; ct < 4; ++ct) {
      const half8_t bf = *(const half8_t*)&Bs[ct * 16 + row16][quad * 8 + kt * 32];
      acc[ct] = __builtin_amdgcn_mfma_f32_16x16x32_f16(af, bf, acc[ct], 0, 0, 0);
    }
  }

#pragma unroll
  for (int ct = 0; ct < 4; ++ct) {
    const int nn = nbase + ct * 16 + row16;     // C col = lane&15
    const float bias = b_ih[nn] + b_hh[nn];
#pragma unroll
    for (int r = 0; r < 4; ++r) {
      const int bb = wave * 16 + quad * 4 + r;  // C row = quad*4 + reg
      U[((size_t)t * BB + bb) * HH + nn] = (_Float16)(acc[ct][r] + bias);
    }
  }
}

// ---------------------------------------------------------------------------
// Part B: recurrence — single barrier per step, ping-pong h, in-wave butterfly.
//   Wave w owns outputs [64w, 64w+64). Lane l: jj=l>>2, kk=l&3.
//   Lane computes k-quarter [64kk,64kk+64) partials for outputs {64w+jj+16m}.
//   h-reads: 8 b128/wave in lane-rotated chunk order c=(i+2kk)&7 so the four
//   kk-groups hit banks 4i+8kk (disjoint -> conflict-free); weights are
//   pre-permuted identically at load time (no runtime register indexing).
//   Reduce over kk via ds_swizzle xor1+xor2 (in-wave, no barrier). Lane
//   finalizes output jstar = 64w+jj+16kk: +u, tanh, one ds_write_b16.
//   ONE __syncthreads per step; read hbuf[t&1], write hbuf[(t+1)&1].
// ---------------------------------------------------------------------------
__global__ __launch_bounds__(256, 1) void rnn_scan_kernel(
    const _Float16* __restrict__ U, const _Float16* __restrict__ WhhT,
    float* __restrict__ out) {
  const int b = blockIdx.x;
  const int tid = threadIdx.x;
  const int w = tid >> 6;
  const int l = tid & 63;
  const int jj = l >> 2;
  const int kk = l & 3;

  __shared__ __align__(16) _Float16 hbuf[2][HH];  // 1 KB ping-pong

  // wreg[m][i] = W^T[64w+jj+16m][64kk + 8*((i+2kk)&7) .. +8)
  half8_t wreg[4][8];
#pragma unroll
  for (int m = 0; m < 4; ++m) {
    const _Float16* base = WhhT + (size_t)(64 * w + jj + 16 * m) * HH + 64 * kk;
#pragma unroll
    for (int i = 0; i < 8; ++i) {
      const int c = (i + 2 * kk) & 7;
      wreg[m][i] = *(const half8_t*)(base + 8 * c);
    }
  }

  hbuf[0][tid] = (_Float16)0.f;  // h0 = 0

  const int jstar = 64 * w + jj + 16 * kk;  // output this lane finalizes
  const _Float16* Up = U + b * HH + jstar;
  _Float16 uA = Up[0];
  _Float16 uB = Up[(size_t)BB * HH];
  float hn = 0.f;
  __syncthreads();

  for (int t = 0; t < TT; ++t) {
    // ---- h-quarter reads, bank-rotated chunk order ----
    const _Float16* hrow = hbuf[t & 1] + 64 * kk;
    half8_t hv[8];
#pragma unroll
    for (int i = 0; i < 8; ++i) {
      const int c = (i + 2 * kk) & 7;
      hv[i] = *(const half8_t*)(hrow + 8 * c);
    }

    // ---- partial dots: 4 outputs x 64 MACs = 128 fdot2, 4 chains ----
    float pa[4] = {0.f, 0.f, 0.f, 0.f};
#pragma unroll
    for (int i = 0; i < 8; ++i) {
      const half8_t h8 = hv[i];
#pragma unroll
      for (int m = 0; m < 4; ++m) {
        const half8_t w8 = wreg[m][i];
        pa[m] = __builtin_amdgcn_fdot2((half2_t){h8[0], h8[1]}, (half2_t){w8[0], w8[1]}, pa[m], false);
        pa[m] = __builtin_amdgcn_fdot2((half2_t){h8[2], h8[3]}, (half2_t){w8[2], w8[3]}, pa[m], false);
        pa[m] = __builtin_amdgcn_fdot2((half2_t){h8[4], h8[5]}, (half2_t){w8[4], w8[5]}, pa[m], false);
        pa[m] = __builtin_amdgcn_fdot2((half2_t){h8[6], h8[7]}, (half2_t){w8[6], w8[7]}, pa[m], false);
      }
    }

    // ---- in-wave butterfly over the 4 k-quarters (xor1 then xor2) ----
#pragma unroll
    for (int m = 0; m < 4; ++m) {
      pa[m] += __int_as_float(__builtin_amdgcn_ds_swizzle(__float_as_int(pa[m]), 0x041F));
      pa[m] += __int_as_float(__builtin_amdgcn_ds_swizzle(__float_as_int(pa[m]), 0x081F));
    }
    // lane finalizes output m == kk (cndmask chain, no runtime reg index)
    const float sum = (kk & 1) ? ((kk & 2) ? pa[3] : pa[1])
                               : ((kk & 2) ? pa[2] : pa[0]);

    const float a = (float)uA + sum;
    // tanh(a) = 1 - 2/(exp(2a)+1)
    const float e = __builtin_amdgcn_exp2f(a * 2.885390081777927f);  // 2*log2(e)
    hn = 1.f - 2.f * __builtin_amdgcn_rcpf(e + 1.f);
    hbuf[(t + 1) & 1][jstar] = (_Float16)hn;

    // u prefetch, 2 steps of distance (use-before-issue keeps vmcnt off path)
    uA = uB;
    uB = Up[(size_t)((t + 2) & (TT - 1)) * (BB * HH)];

    __syncthreads();  // the single per-step barrier
  }
  out[(size_t)b * HH + jstar] = hn;
}

// ---------------------------------------------------------------------------
extern "C" void kernel_launch(void* const* d_in, const int* in_sizes, int n_in,
                              void* d_out, int out_size, void* d_ws, size_t ws_size,
                              hipStream_t stream) {
  const int*   source = (const int*)d_in[0];
  const float* emb    = (const float*)d_in[1];
  const float* Wih    = (const float*)d_in[2];
  const float* Whh    = (const float*)d_in[3];
  const float* bih    = (const float*)d_in[4];
  const float* bhh    = (const float*)d_in[5];
  float* out = (float*)d_out;

  char* ws = (char*)d_ws;
  _Float16* U    = (_Float16*)ws;                    // 2048*64*256*2 = 67,108,864 B
  _Float16* WihT = (_Float16*)(ws + 67108864);       // 131,072 B
  _Float16* WhhT = (_Float16*)(ws + 67239936);       // 131,072 B (total ~67.4 MB)

  prep_kernel<<<dim3(256), dim3(256), 0, stream>>>(Wih, Whh, WihT, WhhT);
  embed_gemm_kernel<<<dim3(TT, 4), dim3(256), 0, stream>>>(source, emb, WihT, bih, bhh, U);
  rnn_scan_kernel<<<dim3(BB), dim3(256), 0, stream>>>(U, WhhT, out);
}

// Round 4
// 1061.809 us; speedup vs baseline: 1.2527x; 1.1580x over previous
//
#include <hip/hip_runtime.h>

#define TT 2048
#define BB 64
#define HH 256   // EMB == HID == 256

typedef _Float16 half2_t __attribute__((ext_vector_type(2)));
typedef _Float16 half8_t __attribute__((ext_vector_type(8)));
typedef float f32x4 __attribute__((ext_vector_type(4)));
typedef int i32x4 __attribute__((ext_vector_type(4)));

static __device__ __forceinline__ float dot2i(int h, int w, float acc) {
  return __builtin_amdgcn_fdot2(__builtin_bit_cast(half2_t, h),
                                __builtin_bit_cast(half2_t, w), acc, false);
}

// ---------------------------------------------------------------------------
// prep: transpose + fp16-convert W_ih and W_hh into [N][K] row-major.
// ---------------------------------------------------------------------------
__global__ void prep_kernel(const float* __restrict__ Wih, const float* __restrict__ Whh,
                            _Float16* __restrict__ WihT, _Float16* __restrict__ WhhT) {
  const int n = blockIdx.x;   // output column
  const int k = threadIdx.x;  // input row
  WihT[n * HH + k] = (_Float16)Wih[k * HH + n];
  WhhT[n * HH + k] = (_Float16)Whh[k * HH + n];
}

// ---------------------------------------------------------------------------
// Part A: U[t][b][n] = (emb[source[b][t]] @ W_ih)[n] + b_ih[n] + b_hh[n], fp16.
// (unchanged — verified correct; scan dominates runtime)
// ---------------------------------------------------------------------------
__global__ __launch_bounds__(256, 2) void embed_gemm_kernel(
    const int* __restrict__ source, const float* __restrict__ emb,
    const _Float16* __restrict__ WihT, const float* __restrict__ b_ih,
    const float* __restrict__ b_hh, _Float16* __restrict__ U) {
  const int t = blockIdx.x;
  const int nbase = blockIdx.y * 64;
  __shared__ __align__(16) _Float16 Bs[64][280];

  const int tid = threadIdx.x;
  for (int c = tid; c < 64 * 32; c += 256) {
    const int n = c >> 5;
    const int ko = (c & 31) * 8;
    *(half8_t*)&Bs[n][ko] = *(const half8_t*)(WihT + (size_t)(nbase + n) * HH + ko);
  }
  __syncthreads();

  const int lane = tid & 63;
  const int wave = tid >> 6;
  const int row16 = lane & 15;
  const int quad = lane >> 4;
  const int b = wave * 16 + row16;              // A-fragment row = batch
  const int src = source[b * TT + t];           // source is [B][T]
  const float* arow = emb + (size_t)src * HH + quad * 8;

  f32x4 acc[4];
#pragma unroll
  for (int ct = 0; ct < 4; ++ct) acc[ct] = (f32x4){0.f, 0.f, 0.f, 0.f};

#pragma unroll
  for (int kt = 0; kt < 8; ++kt) {
    const float4 x0 = *(const float4*)(arow + kt * 32);
    const float4 x1 = *(const float4*)(arow + kt * 32 + 4);
    half8_t af;
    af[0] = (_Float16)x0.x; af[1] = (_Float16)x0.y;
    af[2] = (_Float16)x0.z; af[3] = (_Float16)x0.w;
    af[4] = (_Float16)x1.x; af[5] = (_Float16)x1.y;
    af[6] = (_Float16)x1.z; af[7] = (_Float16)x1.w;
#pragma unroll
    for (int ct = 0; ct < 4; ++ct) {
      const half8_t bf = *(const half8_t*)&Bs[ct * 16 + row16][quad * 8 + kt * 32];
      acc[ct] = __builtin_amdgcn_mfma_f32_16x16x32_f16(af, bf, acc[ct], 0, 0, 0);
    }
  }

#pragma unroll
  for (int ct = 0; ct < 4; ++ct) {
    const int nn = nbase + ct * 16 + row16;     // C col = lane&15
    const float bias = b_ih[nn] + b_hh[nn];
#pragma unroll
    for (int r = 0; r < 4; ++r) {
      const int bb = wave * 16 + quad * 4 + r;  // C row = quad*4 + reg
      U[((size_t)t * BB + bb) * HH + nn] = (_Float16)(acc[ct][r] + bias);
    }
  }
}

// ---------------------------------------------------------------------------
// Part B: recurrence. R3 structure (single barrier, ping-pong h, in-wave
// k-split: jj=l>>2 outputs, kk=l&3 k-quarter, bank-rotated h chunks) with:
//  (1) weights PINNED in 128 VGPRs via asm "+v" after the one-time load —
//      defeats the rematerializer that was re-issuing 32 global_load_dwordx4
//      per step (VGPR_Count was 84 < the 128 the weights need: smoking gun);
//  (2) int-typed fragments, bit_cast at fdot2 — no pack insts;
//  (3) kk-reduction via DPP quad_perm (VALU) instead of 2 dependent
//      ds_swizzle hops (~240 cy of DS latency removed).
// ---------------------------------------------------------------------------
__global__ __launch_bounds__(256, 1) void rnn_scan_kernel(
    const _Float16* __restrict__ U, const _Float16* __restrict__ WhhT,
    float* __restrict__ out) {
  const int b = blockIdx.x;
  const int tid = threadIdx.x;
  const int w = tid >> 6;
  const int l = tid & 63;
  const int jj = l >> 2;
  const int kk = l & 3;

  __shared__ __align__(16) _Float16 hbuf[2][HH];  // 1 KB ping-pong

  // wr[m][i][c]: halfs {2c,2c+1} of W^T[64w+jj+16m][64kk + 8*((i+2kk)&7) ..]
  int wr[4][8][4];
#pragma unroll
  for (int m = 0; m < 4; ++m) {
    const _Float16* base = WhhT + (size_t)(64 * w + jj + 16 * m) * HH + 64 * kk;
#pragma unroll
    for (int i = 0; i < 8; ++i) {
      const int c = (i + 2 * kk) & 7;
      const i32x4 v = *(const i32x4*)(base + 8 * c);
      wr[m][i][0] = v[0]; wr[m][i][1] = v[1];
      wr[m][i][2] = v[2]; wr[m][i][3] = v[3];
    }
  }
  // Pin: the asm "writes" each reg -> not rematerializable inside the loop.
#pragma unroll
  for (int m = 0; m < 4; ++m)
#pragma unroll
    for (int i = 0; i < 8; ++i)
#pragma unroll
      for (int c = 0; c < 4; ++c) asm volatile("" : "+v"(wr[m][i][c]));

  hbuf[0][tid] = (_Float16)0.f;  // h0 = 0

  const int jstar = 64 * w + jj + 16 * kk;  // output this lane finalizes
  const _Float16* Up = U + b * HH + jstar;
  _Float16 uA = Up[0];
  _Float16 uB = Up[(size_t)BB * HH];
  float hn = 0.f;
  __syncthreads();

  for (int t = 0; t < TT; ++t) {
    // ---- h-quarter reads, bank-rotated chunk order (conflict-free) ----
    const i32x4* hq = (const i32x4*)(hbuf[t & 1] + 64 * kk);
    i32x4 hv[8];
#pragma unroll
    for (int i = 0; i < 8; ++i) hv[i] = hq[(i + 2 * kk) & 7];

    // ---- partial dots: 4 outputs x 64 MACs = 128 fdot2, 4 indep chains ----
    float pa[4] = {0.f, 0.f, 0.f, 0.f};
#pragma unroll
    for (int i = 0; i < 8; ++i) {
      const i32x4 h4 = hv[i];
#pragma unroll
      for (int m = 0; m < 4; ++m) {
        pa[m] = dot2i(h4[0], wr[m][i][0], pa[m]);
        pa[m] = dot2i(h4[1], wr[m][i][1], pa[m]);
        pa[m] = dot2i(h4[2], wr[m][i][2], pa[m]);
        pa[m] = dot2i(h4[3], wr[m][i][3], pa[m]);
      }
    }

    // ---- reduce over kk (quad lanes) via DPP quad_perm: VALU-speed ----
#pragma unroll
    for (int m = 0; m < 4; ++m) {
      int x = __float_as_int(pa[m]);
      // xor 1: quad_perm [1,0,3,2] = 0xB1
      pa[m] += __int_as_float(__builtin_amdgcn_mov_dpp(x, 0xB1, 0xF, 0xF, true));
      x = __float_as_int(pa[m]);
      // xor 2: quad_perm [2,3,0,1] = 0x4E
      pa[m] += __int_as_float(__builtin_amdgcn_mov_dpp(x, 0x4E, 0xF, 0xF, true));
    }
    // lane finalizes output m == kk (cndmask chain)
    const float sum = (kk & 1) ? ((kk & 2) ? pa[3] : pa[1])
                               : ((kk & 2) ? pa[2] : pa[0]);

    const float a = (float)uA + sum;
    // tanh(a) = 1 - 2/(exp(2a)+1)
    const float e = __builtin_amdgcn_exp2f(a * 2.885390081777927f);  // 2*log2(e)
    hn = 1.f - 2.f * __builtin_amdgcn_rcpf(e + 1.f);
    hbuf[(t + 1) & 1][jstar] = (_Float16)hn;

    // u prefetch, 2 steps ahead (vmcnt off the critical path)
    uA = uB;
    uB = Up[(size_t)((t + 2) & (TT - 1)) * (BB * HH)];

    __syncthreads();  // the single per-step barrier
  }
  out[(size_t)b * HH + jstar] = hn;
}

// ---------------------------------------------------------------------------
extern "C" void kernel_launch(void* const* d_in, const int* in_sizes, int n_in,
                              void* d_out, int out_size, void* d_ws, size_t ws_size,
                              hipStream_t stream) {
  const int*   source = (const int*)d_in[0];
  const float* emb    = (const float*)d_in[1];
  const float* Wih    = (const float*)d_in[2];
  const float* Whh    = (const float*)d_in[3];
  const float* bih    = (const float*)d_in[4];
  const float* bhh    = (const float*)d_in[5];
  float* out = (float*)d_out;

  char* ws = (char*)d_ws;
  _Float16* U    = (_Float16*)ws;                    // 2048*64*256*2 = 67,108,864 B
  _Float16* WihT = (_Float16*)(ws + 67108864);       // 131,072 B
  _Float16* WhhT = (_Float16*)(ws + 67239936);       // 131,072 B (total ~67.4 MB)

  prep_kernel<<<dim3(256), dim3(256), 0, stream>>>(Wih, Whh, WihT, WhhT);
  embed_gemm_kernel<<<dim3(TT, 4), dim3(256), 0, stream>>>(source, emb, WihT, bih, bhh, U);
  rnn_scan_kernel<<<dim3(BB), dim3(256), 0, stream>>>(U, WhhT, out);
}